// Round 3
// baseline (302.753 us; speedup 1.0000x reference)
//
#include <hip/hip_runtime.h>
#include <math.h>

#define B_ROWS 262144

// ws layout (4-byte cells):
//  A: minmax partials: 128 blocks x 22 cells (mapped-uint min[10], max[10], cm, cf)
//  B: hist partials:   128 blocks x 200 u32   at offset 2816
//  C: main partials:   3 x 2048 f32           at offset 28416
#define WS_A 0
#define WS_B 2816
#define WS_C 28416
#define MAIN_BLOCKS 2048
#define N_TILES 4096        // 64-row tiles over 262144 rows

__device__ __forceinline__ unsigned int map_f(float x) {
  unsigned int b = __float_as_uint(x);
  return (b & 0x80000000u) ? ~b : (b | 0x80000000u);
}
__device__ __forceinline__ float unmap_f(unsigned int u) {
  unsigned int b = (u & 0x80000000u) ? (u ^ 0x80000000u) : ~u;
  return __uint_as_float(b);
}

// ---------------- pass 1 over data_encoded: per-column min/max + sex counts ----
__global__ __launch_bounds__(256) void k_minmax(const float* __restrict__ enc,
                                                unsigned int* __restrict__ ws) {
  int tid = threadIdx.x, bid = blockIdx.x;
  const float4* e4 = (const float4*)enc;
  float mn[10], mx[10];
  #pragma unroll
  for (int j = 0; j < 10; j++) { mn[j] = 1e30f; mx[j] = -1e30f; }
  unsigned int cm = 0, cf = 0;
  #pragma unroll
  for (int i = 0; i < 8; i++) {
    size_t g = (size_t)bid * 2048 + i * 256 + tid;
    float4 a = e4[g * 3 + 0], b = e4[g * 3 + 1], c = e4[g * 3 + 2];
    float v[12] = {a.x,a.y,a.z,a.w,b.x,b.y,b.z,b.w,c.x,c.y,c.z,c.w};
    #pragma unroll
    for (int j = 0; j < 10; j++) { mn[j] = fminf(mn[j], v[j]); mx[j] = fmaxf(mx[j], v[j]); }
    cm += (v[11] == 0.0f); cf += (v[11] == 1.0f);
  }
  #pragma unroll
  for (int off = 32; off; off >>= 1) {
    #pragma unroll
    for (int j = 0; j < 10; j++) {
      mn[j] = fminf(mn[j], __shfl_xor(mn[j], off));
      mx[j] = fmaxf(mx[j], __shfl_xor(mx[j], off));
    }
    cm += __shfl_xor(cm, off); cf += __shfl_xor(cf, off);
  }
  __shared__ float smn[4][10], smx[4][10];
  __shared__ unsigned int sc[4][2];
  int wave = tid >> 6, lane = tid & 63;
  if (lane == 0) {
    #pragma unroll
    for (int j = 0; j < 10; j++) { smn[wave][j] = mn[j]; smx[wave][j] = mx[j]; }
    sc[wave][0] = cm; sc[wave][1] = cf;
  }
  __syncthreads();
  unsigned int* out = ws + WS_A + bid * 22;
  if (tid < 10) {
    float m = fminf(fminf(smn[0][tid], smn[1][tid]), fminf(smn[2][tid], smn[3][tid]));
    out[tid] = map_f(m);
  } else if (tid < 20) {
    int j = tid - 10;
    float m = fmaxf(fmaxf(smx[0][j], smx[1][j]), fmaxf(smx[2][j], smx[3][j]));
    out[tid] = map_f(m);
  } else if (tid < 22) {
    int j = tid - 20;
    out[tid] = sc[0][j] + sc[1][j] + sc[2][j] + sc[3][j];
  }
}

// ---------------- pass 2 over data_encoded: histograms ----------------
__global__ __launch_bounds__(256) void k_hist(const float* __restrict__ enc,
                                              unsigned int* __restrict__ ws) {
  __shared__ float mnv[10], wid[10];
  __shared__ unsigned int h[200];
  int tid = threadIdx.x, bid = blockIdx.x;
  for (int i = tid; i < 200; i += 256) h[i] = 0u;
  if (tid < 10) {
    unsigned int umn = 0xFFFFFFFFu, umx = 0u;
    #pragma unroll 4
    for (int b = 0; b < 128; b++) {
      umn = min(umn, ws[WS_A + b * 22 + tid]);
      umx = max(umx, ws[WS_A + b * 22 + 10 + tid]);
    }
    float mn = unmap_f(umn);
    mnv[tid] = mn;
    wid[tid] = fmaxf(unmap_f(umx) - mn, 1e-12f);
  }
  __syncthreads();
  const float4* e4 = (const float4*)enc;
  #pragma unroll
  for (int i = 0; i < 8; i++) {
    size_t g = (size_t)bid * 2048 + i * 256 + tid;
    float4 a = e4[g * 3 + 0], b = e4[g * 3 + 1], c = e4[g * 3 + 2];
    float v[12] = {a.x,a.y,a.z,a.w,b.x,b.y,b.z,b.w,c.x,c.y,c.z,c.w};
    int base = (v[11] == 0.0f) ? 0 : ((v[11] == 1.0f) ? 100 : -1);
    if (base >= 0) {
      #pragma unroll
      for (int cc = 0; cc < 10; cc++) {
        float t = (v[cc] - mnv[cc]) / wid[cc] * 10.0f;  // reference op order
        int bi = min(max((int)floorf(t), 0), 9);
        atomicAdd(&h[base + cc * 10 + bi], 1u);
      }
    }
  }
  __syncthreads();
  if (tid < 200) ws[WS_B + bid * 200 + tid] = h[tid];
}

// ---------------- main pass over decoded + true ----------------
// ONE WAVE per block; 64-row x 99-col flat LDS tile (25344 B -> 6 blocks/CU).
// Staging: flat float4 loads of d and t, aligned ds_write_b128, mse/dot at
// load time. LSE: one full row per lane (zero divergence); stride-99 scalar
// LDS reads = 2-way bank aliasing = free. No inter-wave barriers anywhere:
// 6 independent wave-streams per CU hide each other's load phases.
__global__ __launch_bounds__(64, 2) void k_main(const float* __restrict__ d,
                                                const float* __restrict__ t,
                                                unsigned int* __restrict__ ws) {
  __shared__ float lds[6336];           // 64 rows x 99 cols, flat
  int lane = threadIdx.x, bid = blockIdx.x;
  float mse = 0.f, dot = 0.f, ce = 0.f;

  for (int tileIdx = bid; tileIdx < N_TILES; tileIdx += MAIN_BLOCKS) {
    const float4* d4 = (const float4*)d + (size_t)tileIdx * 1584;
    const float4* t4 = (const float4*)t + (size_t)tileIdx * 1584;
    float4* l4 = (float4*)lds;
    // ---- staging + elementwise terms (1584 float4 per array per tile) ----
    #pragma unroll 5
    for (int f = lane; f < 1584; f += 64) {
      float4 xd = d4[f];
      float4 xt = t4[f];
      l4[f] = xd;                       // aligned ds_write_b128
      int e = f * 4;                    // tile is 6336 elems = 64*99 ≡ 0 mod 99
      int c = e - (e / 99) * 99;        // magic-mul
      float dv[4] = {xd.x, xd.y, xd.z, xd.w};
      float tv[4] = {xt.x, xt.y, xt.z, xt.w};
      #pragma unroll
      for (int k = 0; k < 4; k++) {
        int cc = c + k;
        if (cc >= 99) cc -= 99;
        bool cont = (cc == 0) | ((unsigned)(cc - 55) <= 2u);
        float diff = dv[k] - tv[k];
        if (cont) mse += diff * diff;
        else      dot += tv[k] * dv[k];
      }
    }
    __syncthreads();                    // 1-wave block: near-free in-wave fence
    // ---- per-row logsumexp, one row per lane, straight-line ----
    const float* row = lds + lane * 99;
    float Z;
    Z = 0.f;
    #pragma unroll
    for (int c = 1; c < 8; c++) Z += __expf(row[c]);
    ce += __logf(Z);
    Z = 0.f;
    #pragma unroll
    for (int c = 8; c < 24; c++) Z += __expf(row[c]);
    ce += __logf(Z);
    Z = 0.f;
    #pragma unroll
    for (int c = 24; c < 31; c++) Z += __expf(row[c]);
    ce += __logf(Z);
    Z = 0.f;
    #pragma unroll
    for (int c = 31; c < 45; c++) Z += __expf(row[c]);
    ce += __logf(Z);
    Z = 0.f;
    #pragma unroll
    for (int c = 45; c < 51; c++) Z += __expf(row[c]);
    ce += __logf(Z);
    Z = 0.f;
    #pragma unroll
    for (int c = 51; c < 53; c++) Z += __expf(row[c]);
    ce += __logf(Z);
    Z = 0.f;
    #pragma unroll
    for (int c = 53; c < 55; c++) Z += __expf(row[c]);
    ce += __logf(Z);
    Z = 0.f;
    #pragma unroll
    for (int c = 58; c < 99; c++) Z += __expf(row[c]);
    ce += __logf(Z);
    __syncthreads();                    // before buffer reuse
  }

  // ---- single-wave butterfly reduction, non-atomic partial write ----
  #pragma unroll
  for (int off = 32; off; off >>= 1) {
    mse += __shfl_xor(mse, off);
    dot += __shfl_xor(dot, off);
    ce  += __shfl_xor(ce,  off);
  }
  if (lane == 0) {
    float* C = (float*)(ws + WS_C);
    C[bid]                   = mse;
    C[MAIN_BLOCKS + bid]     = dot;
    C[2 * MAIN_BLOCKS + bid] = ce;
  }
}

// ---------------- finalize ----------------
__global__ __launch_bounds__(256) void k_final(const unsigned int* __restrict__ ws,
                                               float* __restrict__ out) {
  __shared__ float h[200];
  __shared__ float part[256];
  __shared__ float red3[12];
  __shared__ float cnts[2];
  int tid = threadIdx.x;
  if (tid < 200) {
    unsigned int s = 0;
    #pragma unroll 4
    for (int b = 0; b < 128; b++) s += ws[WS_B + b * 200 + tid];
    h[tid] = (float)s;
  }
  if (tid == 200 || tid == 201) {
    unsigned int s = 0;
    #pragma unroll 4
    for (int b = 0; b < 128; b++) s += ws[WS_A + b * 22 + 20 + (tid - 200)];
    cnts[tid - 200] = fmaxf((float)s, 1.0f);
  }
  const float* C = (const float*)(ws + WS_C);
  float msum = 0.f, dsum = 0.f, csum = 0.f;
  for (int i = tid; i < MAIN_BLOCKS; i += 256) {
    msum += C[i]; dsum += C[MAIN_BLOCKS + i]; csum += C[2 * MAIN_BLOCKS + i];
  }
  #pragma unroll
  for (int off = 32; off; off >>= 1) {
    msum += __shfl_xor(msum, off);
    dsum += __shfl_xor(dsum, off);
    csum += __shfl_xor(csum, off);
  }
  int wave = tid >> 6, lane = tid & 63;
  if (lane == 0) { red3[wave] = msum; red3[4 + wave] = dsum; red3[8 + wave] = csum; }
  __syncthreads();
  float term = 0.f;
  if (tid < 100) {
    float mc = h[tid], fc = h[100 + tid];
    if (mc > 0.f && fc > 0.f) {
      float p = mc / cnts[0];
      float q = fc / cnts[1];
      term = p * logf(p / q);
    }
  }
  part[tid] = term;
  __syncthreads();
  for (int s = 128; s; s >>= 1) {
    if (tid < s) part[tid] += part[tid + s];
    __syncthreads();
  }
  if (tid == 0) {
    const float invB = 1.0f / (float)B_ROWS;
    float mse = (red3[0] + red3[1] + red3[2] + red3[3]) * invB;
    float dd  = (red3[4] + red3[5] + red3[6] + red3[7]);
    float cc  = (red3[8] + red3[9] + red3[10] + red3[11]);
    float ce  = (cc - dd) * invB;
    float akld = 0.5f * part[0];
    out[0] = 0.5f * (mse + ce) + akld;
    out[1] = mse;
    out[2] = ce;
    out[3] = akld;
  }
}

extern "C" void kernel_launch(void* const* d_in, const int* in_sizes, int n_in,
                              void* d_out, int out_size, void* d_ws, size_t ws_size,
                              hipStream_t stream) {
  const float* enc = (const float*)d_in[0];   // data_encoded (B,12)
  const float* dec = (const float*)d_in[1];   // data_decoded (B,99)
  const float* tru = (const float*)d_in[2];   // data_true    (B,99)
  unsigned int* ws = (unsigned int*)d_ws;
  float* out = (float*)d_out;

  hipLaunchKernelGGL(k_minmax, dim3(128),         dim3(256), 0, stream, enc, ws);
  hipLaunchKernelGGL(k_hist,   dim3(128),         dim3(256), 0, stream, enc, ws);
  hipLaunchKernelGGL(k_main,   dim3(MAIN_BLOCKS), dim3(64),  0, stream, dec, tru, ws);
  hipLaunchKernelGGL(k_final,  dim3(1),           dim3(256), 0, stream, ws, out);
}

// Round 4
// 273.769 us; speedup vs baseline: 1.1059x; 1.1059x over previous
//
#include <hip/hip_runtime.h>
#include <math.h>

#define B_ROWS 262144

// ws layout (4-byte cells):
//  A: minmax partials: 128 blocks x 22 cells (mapped-uint min[10], max[10], cm, cf)
//  B: hist partials:   128 blocks x 200 u32   at offset 2816
//  C: main partials:   3 x 1536 f32           at offset 28416
#define WS_A 0
#define WS_B 2816
#define WS_C 28416
#define MAIN_BLOCKS 1536    // 6 per CU, all resident (LDS 25.3 KB -> 6 blocks/CU)
#define N_TILES 4096        // 64-row tiles over 262144 rows

__device__ __forceinline__ unsigned int map_f(float x) {
  unsigned int b = __float_as_uint(x);
  return (b & 0x80000000u) ? ~b : (b | 0x80000000u);
}
__device__ __forceinline__ float unmap_f(unsigned int u) {
  unsigned int b = (u & 0x80000000u) ? (u ^ 0x80000000u) : ~u;
  return __uint_as_float(b);
}

// ---------------- pass 1 over data_encoded: per-column min/max + sex counts ----
__global__ __launch_bounds__(256) void k_minmax(const float* __restrict__ enc,
                                                unsigned int* __restrict__ ws) {
  int tid = threadIdx.x, bid = blockIdx.x;
  const float4* e4 = (const float4*)enc;
  float mn[10], mx[10];
  #pragma unroll
  for (int j = 0; j < 10; j++) { mn[j] = 1e30f; mx[j] = -1e30f; }
  unsigned int cm = 0, cf = 0;
  #pragma unroll
  for (int i = 0; i < 8; i++) {
    size_t g = (size_t)bid * 2048 + i * 256 + tid;
    float4 a = e4[g * 3 + 0], b = e4[g * 3 + 1], c = e4[g * 3 + 2];
    float v[12] = {a.x,a.y,a.z,a.w,b.x,b.y,b.z,b.w,c.x,c.y,c.z,c.w};
    #pragma unroll
    for (int j = 0; j < 10; j++) { mn[j] = fminf(mn[j], v[j]); mx[j] = fmaxf(mx[j], v[j]); }
    cm += (v[11] == 0.0f); cf += (v[11] == 1.0f);
  }
  #pragma unroll
  for (int off = 32; off; off >>= 1) {
    #pragma unroll
    for (int j = 0; j < 10; j++) {
      mn[j] = fminf(mn[j], __shfl_xor(mn[j], off));
      mx[j] = fmaxf(mx[j], __shfl_xor(mx[j], off));
    }
    cm += __shfl_xor(cm, off); cf += __shfl_xor(cf, off);
  }
  __shared__ float smn[4][10], smx[4][10];
  __shared__ unsigned int sc[4][2];
  int wave = tid >> 6, lane = tid & 63;
  if (lane == 0) {
    #pragma unroll
    for (int j = 0; j < 10; j++) { smn[wave][j] = mn[j]; smx[wave][j] = mx[j]; }
    sc[wave][0] = cm; sc[wave][1] = cf;
  }
  __syncthreads();
  unsigned int* out = ws + WS_A + bid * 22;
  if (tid < 10) {
    float m = fminf(fminf(smn[0][tid], smn[1][tid]), fminf(smn[2][tid], smn[3][tid]));
    out[tid] = map_f(m);
  } else if (tid < 20) {
    int j = tid - 10;
    float m = fmaxf(fmaxf(smx[0][j], smx[1][j]), fmaxf(smx[2][j], smx[3][j]));
    out[tid] = map_f(m);
  } else if (tid < 22) {
    int j = tid - 20;
    out[tid] = sc[0][j] + sc[1][j] + sc[2][j] + sc[3][j];
  }
}

// ---------------- pass 2 over data_encoded: histograms ----------------
__global__ __launch_bounds__(256) void k_hist(const float* __restrict__ enc,
                                              unsigned int* __restrict__ ws) {
  __shared__ float mnv[10], wid[10];
  __shared__ unsigned int h[200];
  int tid = threadIdx.x, bid = blockIdx.x;
  for (int i = tid; i < 200; i += 256) h[i] = 0u;
  if (tid < 10) {
    unsigned int umn = 0xFFFFFFFFu, umx = 0u;
    #pragma unroll 4
    for (int b = 0; b < 128; b++) {
      umn = min(umn, ws[WS_A + b * 22 + tid]);
      umx = max(umx, ws[WS_A + b * 22 + 10 + tid]);
    }
    float mn = unmap_f(umn);
    mnv[tid] = mn;
    wid[tid] = fmaxf(unmap_f(umx) - mn, 1e-12f);
  }
  __syncthreads();
  const float4* e4 = (const float4*)enc;
  #pragma unroll
  for (int i = 0; i < 8; i++) {
    size_t g = (size_t)bid * 2048 + i * 256 + tid;
    float4 a = e4[g * 3 + 0], b = e4[g * 3 + 1], c = e4[g * 3 + 2];
    float v[12] = {a.x,a.y,a.z,a.w,b.x,b.y,b.z,b.w,c.x,c.y,c.z,c.w};
    int base = (v[11] == 0.0f) ? 0 : ((v[11] == 1.0f) ? 100 : -1);
    if (base >= 0) {
      #pragma unroll
      for (int cc = 0; cc < 10; cc++) {
        float t = (v[cc] - mnv[cc]) / wid[cc] * 10.0f;  // reference op order
        int bi = min(max((int)floorf(t), 0), 9);
        atomicAdd(&h[base + cc * 10 + bi], 1u);
      }
    }
  }
  __syncthreads();
  if (tid < 200) ws[WS_B + bid * 200 + tid] = h[tid];
}

// ---------------- main pass over decoded + true ----------------
// ONE WAVE per block, 64-row x 99-col flat LDS tile (25344 B -> 6 blocks/CU,
// all 1536 blocks resident). Per tile: issue 25 global_load_lds dwordx4 for d
// (direct-to-LDS, no VGPR round trip) + 25 dwordx4 t-loads into regs — the
// whole 50 KB tile is in flight before one __syncthreads() drain (1-wave
// block: barrier is just the vmcnt(0) wait). 50 KB/900cyc ≈ 56 B/cyc >> the
// ~10 B/cyc per-CU HBM share: a single wave saturates its BW slice.
// Then mse/dot from aligned ds_read_b128 d + t regs; then per-lane-row LSE
// (stride-99 scalar LDS reads = 2-way bank aliasing = free).
__global__ __launch_bounds__(64) void k_main(const float* __restrict__ d,
                                             const float* __restrict__ t,
                                             unsigned int* __restrict__ ws) {
  __shared__ float lds[6336];           // 64 rows x 99 cols, flat
  int lane = threadIdx.x, bid = blockIdx.x;
  float mse = 0.f, dot = 0.f, ce = 0.f;

  for (int tileIdx = bid; tileIdx < N_TILES; tileIdx += MAIN_BLOCKS) {
    const float4* d4 = (const float4*)d + (size_t)tileIdx * 1584;
    const float4* t4 = (const float4*)t + (size_t)tileIdx * 1584;

    // ---- phase A: async d -> LDS, 25 fire-and-forget dwordx4 ----
    #pragma unroll
    for (int it = 0; it < 25; ++it) {
      int f = it * 64 + lane;
      if (f < 1584)
        __builtin_amdgcn_global_load_lds(
            (const __attribute__((address_space(1))) void*)(d4 + f),
            (__attribute__((address_space(3))) void*)(lds + it * 256),
            16, 0, 0);
    }
    // ---- phase B: t -> regs, 25 dwordx4 in flight alongside ----
    float4 tv[25];
    #pragma unroll
    for (int it = 0; it < 25; ++it) {
      int f = it * 64 + lane;
      if (f < 1584) tv[it] = t4[f];
      else          tv[it] = make_float4(0.f, 0.f, 0.f, 0.f);
    }
    __syncthreads();   // single drain: d resident in LDS, t resident in regs

    // ---- phase C: mse/dot from LDS d (aligned b128) + t regs ----
    const float4* l4 = (const float4*)lds;
    #pragma unroll
    for (int it = 0; it < 25; ++it) {
      int f = it * 64 + lane;
      if (f < 1584) {
        float4 xd = l4[f];
        float4 xt = tv[it];
        int e = f * 4;
        int c = e - (e / 99) * 99;      // magic-mul const divisor
        float dv[4] = {xd.x, xd.y, xd.z, xd.w};
        float tvv[4] = {xt.x, xt.y, xt.z, xt.w};
        #pragma unroll
        for (int k = 0; k < 4; k++) {
          int cc = c + k;
          if (cc >= 99) cc -= 99;
          bool cont = (cc == 0) | ((unsigned)(cc - 55) <= 2u);
          float diff = dv[k] - tvv[k];
          if (cont) mse += diff * diff;
          else      dot += tvv[k] * dv[k];
        }
      }
    }
    // ---- phase D: per-row logsumexp, one row per lane ----
    const float* row = lds + lane * 99;
    float Z;
    Z = 0.f;
    #pragma unroll
    for (int c = 1; c < 8; c++) Z += __expf(row[c]);
    ce += __logf(Z);
    Z = 0.f;
    #pragma unroll
    for (int c = 8; c < 24; c++) Z += __expf(row[c]);
    ce += __logf(Z);
    Z = 0.f;
    #pragma unroll
    for (int c = 24; c < 31; c++) Z += __expf(row[c]);
    ce += __logf(Z);
    Z = 0.f;
    #pragma unroll
    for (int c = 31; c < 45; c++) Z += __expf(row[c]);
    ce += __logf(Z);
    Z = 0.f;
    #pragma unroll
    for (int c = 45; c < 51; c++) Z += __expf(row[c]);
    ce += __logf(Z);
    Z = 0.f;
    #pragma unroll
    for (int c = 51; c < 53; c++) Z += __expf(row[c]);
    ce += __logf(Z);
    Z = 0.f;
    #pragma unroll
    for (int c = 53; c < 55; c++) Z += __expf(row[c]);
    ce += __logf(Z);
    Z = 0.f;
    #pragma unroll
    for (int c = 58; c < 99; c++) Z += __expf(row[c]);
    ce += __logf(Z);
    __syncthreads();                    // before LDS reuse next tile
  }

  // ---- single-wave butterfly reduction, non-atomic partial write ----
  #pragma unroll
  for (int off = 32; off; off >>= 1) {
    mse += __shfl_xor(mse, off);
    dot += __shfl_xor(dot, off);
    ce  += __shfl_xor(ce,  off);
  }
  if (lane == 0) {
    float* C = (float*)(ws + WS_C);
    C[bid]                   = mse;
    C[MAIN_BLOCKS + bid]     = dot;
    C[2 * MAIN_BLOCKS + bid] = ce;
  }
}

// ---------------- finalize ----------------
__global__ __launch_bounds__(256) void k_final(const unsigned int* __restrict__ ws,
                                               float* __restrict__ out) {
  __shared__ float h[200];
  __shared__ float part[256];
  __shared__ float red3[12];
  __shared__ float cnts[2];
  int tid = threadIdx.x;
  if (tid < 200) {
    unsigned int s = 0;
    #pragma unroll 4
    for (int b = 0; b < 128; b++) s += ws[WS_B + b * 200 + tid];
    h[tid] = (float)s;
  }
  if (tid == 200 || tid == 201) {
    unsigned int s = 0;
    #pragma unroll 4
    for (int b = 0; b < 128; b++) s += ws[WS_A + b * 22 + 20 + (tid - 200)];
    cnts[tid - 200] = fmaxf((float)s, 1.0f);
  }
  const float* C = (const float*)(ws + WS_C);
  float msum = 0.f, dsum = 0.f, csum = 0.f;
  for (int i = tid; i < MAIN_BLOCKS; i += 256) {
    msum += C[i]; dsum += C[MAIN_BLOCKS + i]; csum += C[2 * MAIN_BLOCKS + i];
  }
  #pragma unroll
  for (int off = 32; off; off >>= 1) {
    msum += __shfl_xor(msum, off);
    dsum += __shfl_xor(dsum, off);
    csum += __shfl_xor(csum, off);
  }
  int wave = tid >> 6, lane = tid & 63;
  if (lane == 0) { red3[wave] = msum; red3[4 + wave] = dsum; red3[8 + wave] = csum; }
  __syncthreads();
  float term = 0.f;
  if (tid < 100) {
    float mc = h[tid], fc = h[100 + tid];
    if (mc > 0.f && fc > 0.f) {
      float p = mc / cnts[0];
      float q = fc / cnts[1];
      term = p * logf(p / q);
    }
  }
  part[tid] = term;
  __syncthreads();
  for (int s = 128; s; s >>= 1) {
    if (tid < s) part[tid] += part[tid + s];
    __syncthreads();
  }
  if (tid == 0) {
    const float invB = 1.0f / (float)B_ROWS;
    float mse = (red3[0] + red3[1] + red3[2] + red3[3]) * invB;
    float dd  = (red3[4] + red3[5] + red3[6] + red3[7]);
    float cc  = (red3[8] + red3[9] + red3[10] + red3[11]);
    float ce  = (cc - dd) * invB;
    float akld = 0.5f * part[0];
    out[0] = 0.5f * (mse + ce) + akld;
    out[1] = mse;
    out[2] = ce;
    out[3] = akld;
  }
}

extern "C" void kernel_launch(void* const* d_in, const int* in_sizes, int n_in,
                              void* d_out, int out_size, void* d_ws, size_t ws_size,
                              hipStream_t stream) {
  const float* enc = (const float*)d_in[0];   // data_encoded (B,12)
  const float* dec = (const float*)d_in[1];   // data_decoded (B,99)
  const float* tru = (const float*)d_in[2];   // data_true    (B,99)
  unsigned int* ws = (unsigned int*)d_ws;
  float* out = (float*)d_out;

  hipLaunchKernelGGL(k_minmax, dim3(128),         dim3(256), 0, stream, enc, ws);
  hipLaunchKernelGGL(k_hist,   dim3(128),         dim3(256), 0, stream, enc, ws);
  hipLaunchKernelGGL(k_main,   dim3(MAIN_BLOCKS), dim3(64),  0, stream, dec, tru, ws);
  hipLaunchKernelGGL(k_final,  dim3(1),           dim3(256), 0, stream, ws, out);
}